// Round 1
// baseline (88.192 us; speedup 1.0000x reference)
//
#include <hip/hip_runtime.h>

#define N_ROWS 2048
#define L 128
#define FGV 2.0f
#define CROWS 16   // rows of n staged per block in pair_kernel

__device__ __forceinline__ float waveReduceSum(float v) {
#pragma unroll
    for (int off = 32; off > 0; off >>= 1)
        v += __shfl_down(v, off, 64);
    return v;
}

// ---------------------------------------------------------------------------
// Kernel A: per-element pass. Computes sum(f) and the k==0 (diagonal) loss
// terms: (w0[i,0]*|d| + w1[i,0]*d^2) * f.   acc[0]=sumf, acc[1]=loss.
// Grid sized so each thread handles exactly 4 consecutive elements (float4).
// ---------------------------------------------------------------------------
__global__ __launch_bounds__(256)
void prep_kernel(const float* __restrict__ yt, const float* __restrict__ yp,
                 const float* __restrict__ yd, const float* __restrict__ w,
                 float* __restrict__ acc) {
    int t = blockIdx.x * 256 + threadIdx.x;
    int e0 = t * 4;                       // < N_ROWS*L exactly
    float4 a = *(const float4*)(yt + e0);
    float4 b = *(const float4*)(yp + e0);
    float4 c = *(const float4*)(yd + e0);
    int i0 = e0 & (L - 1);                // column index of first element

    float dv[4] = {a.x - b.x, a.y - b.y, a.z - b.z, a.w - b.w};
    float fv[4] = {fabsf(c.x) <= FGV ? 1.f : 0.f,
                   fabsf(c.y) <= FGV ? 1.f : 0.f,
                   fabsf(c.z) <= FGV ? 1.f : 0.f,
                   fabsf(c.w) <= FGV ? 1.f : 0.f};
    float sumf = 0.f, diag = 0.f;
#pragma unroll
    for (int q = 0; q < 4; q++) {
        float ad = fabsf(dv[q]);
        float f  = fv[q];
        sumf += f;
        int i = i0 + q;
        float w0 = w[i * L];              // weights[0][i][0]
        float w1 = w[L * L + i * L];      // weights[1][i][0]
        diag += f * fmaf(w1, ad * ad, w0 * ad);
    }

    __shared__ float red1[4], red2[4];
    float s  = waveReduceSum(sumf);
    float dg = waveReduceSum(diag);
    int wave = threadIdx.x >> 6, lane = threadIdx.x & 63;
    if (lane == 0) { red1[wave] = s; red2[wave] = dg; }
    __syncthreads();
    if (threadIdx.x == 0) {
        atomicAdd(&acc[0], red1[0] + red1[1] + red1[2] + red1[3]);
        atomicAdd(&acc[1], red2[0] + red2[1] + red2[2] + red2[3]);
    }
}

// ---------------------------------------------------------------------------
// Kernel B: k>=1 pair terms. Tiles over (i, j=i+k):
//   tile 0: i in [0,64),  j in [0,64)    (diagonal, k<=0 auto-zeroed)
//   tile 1: i in [0,64),  j in [64,128)  (fully valid)
//   tile 2: i in [64,128),j in [64,128)  (diagonal)
// Each block: one (tile, n-chunk of CROWS rows). Stage (d,f) rows to LDS,
// register-tile 4x4 pairs/thread, accumulate S1/S2 over n, apply weights in
// epilogue (k<1 -> weight skipped => auto-zero), block-reduce, atomicAdd.
// ---------------------------------------------------------------------------
__global__ __launch_bounds__(256)
void pair_kernel(const float* __restrict__ yt, const float* __restrict__ yp,
                 const float* __restrict__ yd, const float* __restrict__ w,
                 float* __restrict__ acc) {
    const int tile = blockIdx.y;
    const int i0 = (tile == 2) ? 64 : 0;
    const int j0 = (tile == 0) ? 0 : 64;
    const int tid = threadIdx.x;

    __shared__ float2 sh[CROWS][L];   // (d, f) per element, 16 KB
    {
        // CROWS*L = 2048 elements, 8 per thread, contiguous: float4 loads.
        int base = blockIdx.x * (CROWS * L) + tid * 8;
        const float4* t4 = (const float4*)(yt + base);
        const float4* p4 = (const float4*)(yp + base);
        const float4* c4 = (const float4*)(yd + base);
        float2* o = &sh[0][0] + tid * 8;
#pragma unroll
        for (int q = 0; q < 2; q++) {
            float4 aa = t4[q], bb = p4[q], cc = c4[q];
            o[q*4+0] = make_float2(aa.x - bb.x, fabsf(cc.x) <= FGV ? 1.f : 0.f);
            o[q*4+1] = make_float2(aa.y - bb.y, fabsf(cc.y) <= FGV ? 1.f : 0.f);
            o[q*4+2] = make_float2(aa.z - bb.z, fabsf(cc.z) <= FGV ? 1.f : 0.f);
            o[q*4+3] = make_float2(aa.w - bb.w, fabsf(cc.w) <= FGV ? 1.f : 0.f);
        }
    }
    __syncthreads();

    const int tx = tid & 15;   // i fragment selector (strided by 16)
    const int ty = tid >> 4;   // j fragment selector (contiguous by 4)

    float s1[4][4] = {{0.f}};
    float s2[4][4] = {{0.f}};

    for (int n = 0; n < CROWS; n++) {
        float2 vi[4], vj[4];
#pragma unroll
        for (int aq = 0; aq < 4; aq++) vi[aq] = sh[n][i0 + tx + 16*aq];  // b64, conflict-free
#pragma unroll
        for (int bq = 0; bq < 4; bq++) vj[bq] = sh[n][j0 + ty*4 + bq];   // b128 pairs, broadcast
        float ej[4];
#pragma unroll
        for (int bq = 0; bq < 4; bq++) ej[bq] = vj[bq].x * vj[bq].y;     // d_j * f_j
#pragma unroll
        for (int aq = 0; aq < 4; aq++) {
#pragma unroll
            for (int bq = 0; bq < 4; bq++) {
                // t0 = |d_i - d_j| * f_j   (f_j in {0,1} so |f_j*(d_i-d_j)| works)
                float t0 = fabsf(fmaf(vi[aq].x, vj[bq].y, -ej[bq]));
                float t1 = t0 * vi[aq].y;          // * f_i
                s1[aq][bq] += t1;                  // a   * f_i*f_j
                s2[aq][bq] = fmaf(t0, t1, s2[aq][bq]);  // a^2 * f_i*f_j
            }
        }
    }

    // Epilogue: weights (n-independent), k<1 auto-zeroed by skipping.
    float total = 0.f;
#pragma unroll
    for (int aq = 0; aq < 4; aq++) {
        int i = i0 + tx + 16*aq;
#pragma unroll
        for (int bq = 0; bq < 4; bq++) {
            int j = j0 + ty*4 + bq;
            int k = j - i;
            if (k >= 1) {
                total = fmaf(s1[aq][bq], w[i * L + k], total);
                total = fmaf(s2[aq][bq], w[L * L + i * L + k], total);
            }
        }
    }

    __shared__ float red[4];
    float s = waveReduceSum(total);
    int wave = tid >> 6, lane = tid & 63;
    if (lane == 0) red[wave] = s;
    __syncthreads();
    if (tid == 0) atomicAdd(&acc[1], red[0] + red[1] + red[2] + red[3]);
}

// ---------------------------------------------------------------------------
__global__ void fin_kernel(const float* __restrict__ acc, float* __restrict__ out) {
    out[0] = acc[1] / acc[0];
}

extern "C" void kernel_launch(void* const* d_in, const int* in_sizes, int n_in,
                              void* d_out, int out_size, void* d_ws, size_t ws_size,
                              hipStream_t stream) {
    const float* yt = (const float*)d_in[0];
    const float* yp = (const float*)d_in[1];
    const float* yd = (const float*)d_in[2];
    const float* w  = (const float*)d_in[3];
    float* acc = (float*)d_ws;       // acc[0]=sumf, acc[1]=loss
    float* out = (float*)d_out;

    hipMemsetAsync(acc, 0, 2 * sizeof(float), stream);
    prep_kernel<<<dim3((N_ROWS * L) / (256 * 4)), 256, 0, stream>>>(yt, yp, yd, w, acc);
    pair_kernel<<<dim3(N_ROWS / CROWS, 3), 256, 0, stream>>>(yt, yp, yd, w, acc);
    fin_kernel<<<1, 1, 0, stream>>>(acc, out);
}

// Round 2
// 76.862 us; speedup vs baseline: 1.1474x; 1.1474x over previous
//
#include <hip/hip_runtime.h>

#define N_ROWS 2048
#define L 128
#define FGV 2.0f
#define CROWS 16   // rows of n staged per block

// ws layout: partials[0..383] = per-block loss partials (tile*128+bx)
//            partials[384..511] = per-(tile0-block) sum(f) partials
#define NLOSS 384
#define NTOT  512

__device__ __forceinline__ float waveReduceSum(float v) {
#pragma unroll
    for (int off = 32; off > 0; off >>= 1)
        v += __shfl_down(v, off, 64);
    return v;
}

// ---------------------------------------------------------------------------
// Fused kernel: grid (128 n-chunks, 3 (i,j) tiles).
//   tile 0: i in [0,64),  j in [0,64)    -- also computes sum(f) + k==0 terms
//   tile 1: i in [0,64),  j in [64,128)
//   tile 2: i in [64,128),j in [64,128)
// Stage (d,f) for CROWS rows to LDS, register-tile 4x4 pairs/thread,
// accumulate S1=sum(a*fi*fj), S2=sum(a^2*fi*fj) over n in registers, apply
// n-independent weights in the epilogue (k<1 skipped => auto-zero), block
// reduce, write partial to its own ws slot (no zero-init / atomics needed).
// ---------------------------------------------------------------------------
__global__ __launch_bounds__(256)
void fused_kernel(const float* __restrict__ yt, const float* __restrict__ yp,
                  const float* __restrict__ yd, const float* __restrict__ w,
                  float* __restrict__ partials) {
    const int tile = blockIdx.y;
    const int i0 = (tile == 2) ? 64 : 0;
    const int j0 = (tile == 0) ? 0 : 64;
    const int tid = threadIdx.x;

    __shared__ float2 sh[CROWS][L];   // (d, f) per element, 16 KB

    float sumf = 0.f;   // only tile 0 accumulates
    float diag = 0.f;   // k==0 loss terms, only tile 0
    {
        // CROWS*L = 2048 elements, 8 per thread, contiguous: float4 loads.
        int base = blockIdx.x * (CROWS * L) + tid * 8;
        const float4* t4 = (const float4*)(yt + base);
        const float4* p4 = (const float4*)(yp + base);
        const float4* c4 = (const float4*)(yd + base);
        float2* o = &sh[0][0] + tid * 8;
#pragma unroll
        for (int q = 0; q < 2; q++) {
            float4 aa = t4[q], bb = p4[q], cc = c4[q];
            float d[4] = {aa.x - bb.x, aa.y - bb.y, aa.z - bb.z, aa.w - bb.w};
            float f[4] = {fabsf(cc.x) <= FGV ? 1.f : 0.f,
                          fabsf(cc.y) <= FGV ? 1.f : 0.f,
                          fabsf(cc.z) <= FGV ? 1.f : 0.f,
                          fabsf(cc.w) <= FGV ? 1.f : 0.f};
#pragma unroll
            for (int e = 0; e < 4; e++) {
                o[q * 4 + e] = make_float2(d[e], f[e]);
                if (tile == 0) {   // block-uniform branch, no divergence
                    int i = (tid * 8 + q * 4 + e) & (L - 1);
                    float ad = fabsf(d[e]);
                    sumf += f[e];
                    // weights[0][i][0] and weights[1][i][0]
                    diag += f[e] * fmaf(w[L * L + i * L], ad * ad,
                                        w[i * L] * ad);
                }
            }
        }
    }
    __syncthreads();

    const int tx = tid & 15;   // i fragment (strided by 16 -> conflict-free b64)
    const int ty = tid >> 4;   // j fragment (contiguous by 4 -> b128 broadcast)

    float s1[4][4] = {{0.f}};
    float s2[4][4] = {{0.f}};

    for (int n = 0; n < CROWS; n++) {
        float2 vi[4], vj[4];
#pragma unroll
        for (int aq = 0; aq < 4; aq++) vi[aq] = sh[n][i0 + tx + 16 * aq];
#pragma unroll
        for (int bq = 0; bq < 4; bq++) vj[bq] = sh[n][j0 + ty * 4 + bq];
        float ej[4];
#pragma unroll
        for (int bq = 0; bq < 4; bq++) ej[bq] = vj[bq].x * vj[bq].y;  // d_j*f_j
#pragma unroll
        for (int aq = 0; aq < 4; aq++) {
#pragma unroll
            for (int bq = 0; bq < 4; bq++) {
                // t0 = |d_i - d_j| * f_j  (f_j in {0,1} so abs(fma) works)
                float t0 = fabsf(fmaf(vi[aq].x, vj[bq].y, -ej[bq]));
                float t1 = t0 * vi[aq].y;               // * f_i
                s1[aq][bq] += t1;                       // a   * fi*fj
                s2[aq][bq] = fmaf(t0, t1, s2[aq][bq]);  // a^2 * fi*fj
            }
        }
    }

    // Epilogue: apply n-independent weights; k<1 skipped (auto-zero).
    float total = diag;
#pragma unroll
    for (int aq = 0; aq < 4; aq++) {
        int i = i0 + tx + 16 * aq;
#pragma unroll
        for (int bq = 0; bq < 4; bq++) {
            int j = j0 + ty * 4 + bq;
            int k = j - i;
            if (k >= 1) {
                total = fmaf(s1[aq][bq], w[i * L + k], total);
                total = fmaf(s2[aq][bq], w[L * L + i * L + k], total);
            }
        }
    }

    // Block-reduce (loss, sumf) and write this block's ws slots.
    __shared__ float redL[4], redF[4];
    float sL = waveReduceSum(total);
    float sF = waveReduceSum(sumf);
    int wave = tid >> 6, lane = tid & 63;
    if (lane == 0) { redL[wave] = sL; redF[wave] = sF; }
    __syncthreads();
    if (tid == 0) {
        partials[tile * 128 + blockIdx.x] = redL[0] + redL[1] + redL[2] + redL[3];
        if (tile == 0)
            partials[NLOSS + blockIdx.x] = redF[0] + redF[1] + redF[2] + redF[3];
    }
}

// ---------------------------------------------------------------------------
// Final reduction: 512 partials -> out[0] = loss_total / sumf_total.
// ---------------------------------------------------------------------------
__global__ __launch_bounds__(256)
void fin_kernel(const float* __restrict__ partials, float* __restrict__ out) {
    int tid = threadIdx.x;
    float lossAcc = 0.f, fAcc = 0.f;
#pragma unroll
    for (int idx = tid; idx < NTOT; idx += 256) {
        float v = partials[idx];
        if (idx < NLOSS) lossAcc += v; else fAcc += v;
    }
    __shared__ float redL[4], redF[4];
    float sL = waveReduceSum(lossAcc);
    float sF = waveReduceSum(fAcc);
    int wave = tid >> 6, lane = tid & 63;
    if (lane == 0) { redL[wave] = sL; redF[wave] = sF; }
    __syncthreads();
    if (tid == 0) {
        float loss = redL[0] + redL[1] + redL[2] + redL[3];
        float fsum = redF[0] + redF[1] + redF[2] + redF[3];
        out[0] = loss / fsum;
    }
}

extern "C" void kernel_launch(void* const* d_in, const int* in_sizes, int n_in,
                              void* d_out, int out_size, void* d_ws, size_t ws_size,
                              hipStream_t stream) {
    const float* yt = (const float*)d_in[0];
    const float* yp = (const float*)d_in[1];
    const float* yd = (const float*)d_in[2];
    const float* w  = (const float*)d_in[3];
    float* partials = (float*)d_ws;   // 512 floats, all written every call
    float* out = (float*)d_out;

    fused_kernel<<<dim3(N_ROWS / CROWS, 3), 256, 0, stream>>>(yt, yp, yd, w, partials);
    fin_kernel<<<1, 256, 0, stream>>>(partials, out);
}

// Round 3
// 67.652 us; speedup vs baseline: 1.3036x; 1.1361x over previous
//
#include <hip/hip_runtime.h>

#define N_ROWS 2048
#define L 128
#define FGV 2.0f
#define CROWS 8    // rows of n staged per block -> 768 blocks = 3/CU exactly

// ws layout: partials[0..767]    = per-block loss partials (tile*256+bx)
//            partials[768..1023] = per-(tile0-block) sum(f) partials
#define NLOSS 768
#define NTOT  1024

__device__ __forceinline__ float waveReduceSum(float v) {
#pragma unroll
    for (int off = 32; off > 0; off >>= 1)
        v += __shfl_down(v, off, 64);
    return v;
}

// ---------------------------------------------------------------------------
// Fused kernel: grid (256 n-chunks, 3 (i,j) tiles).
//   tile 0: i in [0,64),  j in [0,64)    -- also computes sum(f) + k==0 terms
//   tile 1: i in [0,64),  j in [64,128)
//   tile 2: i in [64,128),j in [64,128)
// Stage (d,f) for CROWS rows to LDS, register-tile 4x4 pairs/thread,
// accumulate S1=sum(a*fi*fj), S2=sum(a^2*fi*fj) over n in registers, apply
// n-independent weights in the epilogue (k<1 skipped => auto-zero), block
// reduce, write partial to this block's own ws slot (no zero-init/atomics).
// ---------------------------------------------------------------------------
__global__ __launch_bounds__(256)
void fused_kernel(const float* __restrict__ yt, const float* __restrict__ yp,
                  const float* __restrict__ yd, const float* __restrict__ w,
                  float* __restrict__ partials) {
    const int tile = blockIdx.y;
    const int i0 = (tile == 2) ? 64 : 0;
    const int j0 = (tile == 0) ? 0 : 64;
    const int tid = threadIdx.x;

    __shared__ float2 sh[CROWS][L];   // (d, f) per element, 8 KB

    float sumf = 0.f;   // only tile 0 accumulates
    float diag = 0.f;   // k==0 loss terms, only tile 0
    {
        // CROWS*L = 1024 elements, exactly one float4 per thread per array.
        int base = blockIdx.x * (CROWS * L) + tid * 4;
        float4 aa = *(const float4*)(yt + base);
        float4 bb = *(const float4*)(yp + base);
        float4 cc = *(const float4*)(yd + base);
        float d[4] = {aa.x - bb.x, aa.y - bb.y, aa.z - bb.z, aa.w - bb.w};
        float f[4] = {fabsf(cc.x) <= FGV ? 1.f : 0.f,
                      fabsf(cc.y) <= FGV ? 1.f : 0.f,
                      fabsf(cc.z) <= FGV ? 1.f : 0.f,
                      fabsf(cc.w) <= FGV ? 1.f : 0.f};
        float2* o = &sh[0][0] + tid * 4;
#pragma unroll
        for (int e = 0; e < 4; e++) {
            o[e] = make_float2(d[e], f[e]);
            if (tile == 0) {   // block-uniform branch, no divergence
                int i = (tid * 4 + e) & (L - 1);
                float ad = fabsf(d[e]);
                sumf += f[e];
                // weights[0][i][0] and weights[1][i][0]
                diag += f[e] * fmaf(w[L * L + i * L], ad * ad, w[i * L] * ad);
            }
        }
    }
    __syncthreads();

    const int tx = tid & 15;   // i fragment (strided by 16 -> conflict-free)
    const int ty = tid >> 4;   // j fragment (contiguous by 4 -> b128 broadcast)

    float s1[4][4] = {{0.f}};
    float s2[4][4] = {{0.f}};

#pragma unroll 2
    for (int n = 0; n < CROWS; n++) {
        float2 vi[4], vj[4];
#pragma unroll
        for (int aq = 0; aq < 4; aq++) vi[aq] = sh[n][i0 + tx + 16 * aq];
#pragma unroll
        for (int bq = 0; bq < 4; bq++) vj[bq] = sh[n][j0 + ty * 4 + bq];
        float ej[4];
#pragma unroll
        for (int bq = 0; bq < 4; bq++) ej[bq] = vj[bq].x * vj[bq].y;  // d_j*f_j
#pragma unroll
        for (int aq = 0; aq < 4; aq++) {
#pragma unroll
            for (int bq = 0; bq < 4; bq++) {
                // t0 = |d_i - d_j| * f_j  (f_j in {0,1} so abs(fma) works)
                float t0 = fabsf(fmaf(vi[aq].x, vj[bq].y, -ej[bq]));
                float t1 = t0 * vi[aq].y;               // * f_i
                s1[aq][bq] += t1;                       // a   * fi*fj
                s2[aq][bq] = fmaf(t0, t1, s2[aq][bq]);  // a^2 * fi*fj
            }
        }
    }

    // Epilogue: apply n-independent weights; k<1 skipped (auto-zero).
    float total = diag;
#pragma unroll
    for (int aq = 0; aq < 4; aq++) {
        int i = i0 + tx + 16 * aq;
#pragma unroll
        for (int bq = 0; bq < 4; bq++) {
            int j = j0 + ty * 4 + bq;
            int k = j - i;
            if (k >= 1) {
                total = fmaf(s1[aq][bq], w[i * L + k], total);
                total = fmaf(s2[aq][bq], w[L * L + i * L + k], total);
            }
        }
    }

    // Block-reduce (loss, sumf) and write this block's ws slots.
    __shared__ float redL[4], redF[4];
    float sL = waveReduceSum(total);
    float sF = waveReduceSum(sumf);
    int wave = tid >> 6, lane = tid & 63;
    if (lane == 0) { redL[wave] = sL; redF[wave] = sF; }
    __syncthreads();
    if (tid == 0) {
        partials[tile * 256 + blockIdx.x] = redL[0] + redL[1] + redL[2] + redL[3];
        if (tile == 0)
            partials[NLOSS + blockIdx.x] = redF[0] + redF[1] + redF[2] + redF[3];
    }
}

// ---------------------------------------------------------------------------
// Final reduction: one wave, float4 loads. 1024 floats = 256 float4s.
// float4 idx t, t+64, t+128 -> loss; idx t+192 -> sumf.
// ---------------------------------------------------------------------------
__global__ __launch_bounds__(64)
void fin_kernel(const float* __restrict__ partials, float* __restrict__ out) {
    int t = threadIdx.x;
    const float4* p4 = (const float4*)partials;
    float lossAcc = 0.f, fAcc = 0.f;
#pragma unroll
    for (int q = 0; q < 3; q++) {
        float4 v = p4[t + q * 64];
        lossAcc += (v.x + v.y) + (v.z + v.w);
    }
    {
        float4 v = p4[t + 192];
        fAcc = (v.x + v.y) + (v.z + v.w);
    }
    float sL = waveReduceSum(lossAcc);
    float sF = waveReduceSum(fAcc);
    if (t == 0) out[0] = sL / sF;
}

extern "C" void kernel_launch(void* const* d_in, const int* in_sizes, int n_in,
                              void* d_out, int out_size, void* d_ws, size_t ws_size,
                              hipStream_t stream) {
    const float* yt = (const float*)d_in[0];
    const float* yp = (const float*)d_in[1];
    const float* yd = (const float*)d_in[2];
    const float* w  = (const float*)d_in[3];
    float* partials = (float*)d_ws;   // 1024 floats, all written every call
    float* out = (float*)d_out;

    fused_kernel<<<dim3(N_ROWS / CROWS, 3), 256, 0, stream>>>(yt, yp, yd, w, partials);
    fin_kernel<<<1, 64, 0, stream>>>(partials, out);
}